// Round 7
// baseline (240.941 us; speedup 1.0000x reference)
//
#include <hip/hip_runtime.h>
#include <math.h>

#define IMG_H 2048
#define IMG_W 2048
#define NB    8
#define BORDER 10
#define REP_THR 0.6f
#define SH 64          // output rows per thread (strip height)

typedef float f32x4 __attribute__((ext_vector_type(4)));

// Register-rolling column-strip NMS, prefetch distance 2.
//
// Model from rounds 0-6: clean streaming kernels on this machine pin at
// ~6.5 TB/s of CU<->L2 fabric demand (fill 537MB/83us, R6 ~536MB/82us,
// R0 ~360MB/62us), NOT at HBM (FETCH=65MB only). The lever is fabric
// traffic: vertical 3x re-reads must be absorbed in REGISTERS, not L2.
// This kernel: each thread walks a 64-row x 4-col strip; every input line
// crosses the fabric once (amp 66/64 = 1.03). Fabric = 134*1.03 + 134
// writes = 276 MB -> ~43us at the 6.5 TB/s wall.
//
// Why the structure is this explicit: R1 (distance-1 rolling) serialized
// load->use; R2/R3 (hoist-all) hit the allocator wall (VGPR capped 32-40,
// loads re-sunk); R4 (LDS) died on drain barriers at 2 blocks/CU. Here:
//   - prefetch distance 2: row j+4 issued at iter j, consumed at iter j+2
//     (2 pending slots, statically named, period-2);
//   - h-window statically rotated period-4 => everything stays in regs;
//   - sched_barrier(0) after each sub-iteration: the scheduler may NOT
//     sink a prefetch down to its consumer (the exact R1-R3 failure);
//   - __launch_bounds__(256,2): ~128 VGPR budget, allocator unconstrained
//     (~55 live floats). 8 waves/CU x 2 rows in flight covers latency.
//
// Loads are clamped to rows [9,2038]: out-of-range rows feed only
// border-masked outputs; all addresses stay in-bounds (incl. the -1/+4
// column halos, which only ever reach adjacent in-image bytes).
// All outputs masked by bx/rowok; no divergent fast paths at all.
__global__ __launch_bounds__(256, 2) void nms_kernel(const float* __restrict__ in,
                                                     float* __restrict__ out) {
    // 512 blocks = 8 XCDs x 64: XCD k owns image k; inter-strip halo
    // re-reads (2 rows per 64) stay in one XCD's L2.
    const int orig = blockIdx.x;
    const int swz  = (orig & 7) * 64 + (orig >> 3);
    const int tid  = (swz << 8) | (int)threadIdx.x;   // 17 bits

    const int gx    = tid & 511;          // 4-col group
    const int strip = (tid >> 9) & 31;    // block-uniform
    const int b     = tid >> 14;          // block-uniform

    const int x4 = gx << 2;               // 0..2044
    const int y0 = strip << 6;             // 0..1984

    const size_t img_off = (size_t)b * IMG_H * IMG_W;
    const float* ibase = in  + img_off + x4;
    float*       obase = out + img_off + (size_t)y0 * IMG_W + x4;

    const bool bx0 = (x4 + 0 >= BORDER) && (x4 + 0 < IMG_W - BORDER);
    const bool bx1 = (x4 + 1 >= BORDER) && (x4 + 1 < IMG_W - BORDER);
    const bool bx2 = (x4 + 2 >= BORDER) && (x4 + 2 < IMG_W - BORDER);
    const bool bx3 = (x4 + 3 >= BORDER) && (x4 + 3 < IMG_W - BORDER);

#define CLAMPR(r) ((r) < (BORDER - 1) ? (BORDER - 1) \
                 : ((r) > (IMG_H - BORDER) ? (IMG_H - BORDER) : (r)))

#define ISSUE(row, V, L, Q) do {                                  \
        const float* _p = ibase + (size_t)CLAMPR(row) * IMG_W;    \
        (V) = *(const f32x4*)_p;                                  \
        (L) = _p[-1];                                             \
        (Q) = _p[4];                                              \
    } while (0)

#define HMAX(H, V, L, Q) do {                                     \
        (H)[0] = fmaxf((L),    fmaxf((V)[0], (V)[1]));            \
        (H)[1] = fmaxf((V)[0], fmaxf((V)[1], (V)[2]));            \
        (H)[2] = fmaxf((V)[1], fmaxf((V)[2], (V)[3]));            \
        (H)[3] = fmaxf((V)[2], fmaxf((V)[3], (V)[3] > (Q) ? (Q) : (Q))); \
    } while (0)

    // NOTE: H[3] must be max(V[2],V[3],Q) — keep it straightforward:
#undef HMAX
#define HMAX(H, V, L, Q) do {                                     \
        (H)[0] = fmaxf((L),    fmaxf((V)[0], (V)[1]));            \
        (H)[1] = fmaxf((V)[0], fmaxf((V)[1], (V)[2]));            \
        (H)[2] = fmaxf((V)[1], fmaxf((V)[2], (V)[3]));            \
        (H)[3] = fmaxf((V)[2], fmaxf((V)[3], (Q)));               \
    } while (0)

    // ---- Prologue: rows y0-1..y0+3 ----
    f32x4 vA, vB, vC;
    float lA, qA, lB, qB, lC, qC;
    ISSUE(y0 - 1, vA, lA, qA);
    ISSUE(y0 + 0, vB, lB, qB);
    ISSUE(y0 + 1, vC, lC, qC);

    f32x4 pV0; float pL0, pQ0;
    f32x4 pV1; float pL1, pQ1;
    ISSUE(y0 + 2, pV0, pL0, pQ0);   // pending slot 0 (consumed at iter 0)
    ISSUE(y0 + 3, pV1, pL1, pQ1);   // pending slot 1 (consumed at iter 1)

    f32x4 hS0, hS1, hS2, hS3;
    HMAX(hS0, vA, lA, qA);          // h(y0-1)
    HMAX(hS1, vB, lB, qB);          // h(y0)
    HMAX(hS2, vC, lC, qC);          // h(y0+1)
    f32x4 vs0 = vB;                 // center vals of row y0   (for iter 0)
    f32x4 vs1 = vC;                 // center vals of row y0+1 (for iter 1)

    // ---- Steady loop: iter j emits row y0+j, computes h(row j+2) from the
    //      pending slot, and re-issues that slot for row j+4 (distance 2). ----
#define ITER(j, Hm1, H0, Hp1, Hp2, PV, PL, PQ, VS) do {                   \
        const int _y = y0 + (j);                                          \
        f32x4 _m;                                                         \
        _m[0] = fmaxf((Hm1)[0], fmaxf((H0)[0], (Hp1)[0]));                \
        _m[1] = fmaxf((Hm1)[1], fmaxf((H0)[1], (Hp1)[1]));                \
        _m[2] = fmaxf((Hm1)[2], fmaxf((H0)[2], (Hp1)[2]));                \
        _m[3] = fmaxf((Hm1)[3], fmaxf((H0)[3], (Hp1)[3]));                \
        const bool _rowok = (_y >= BORDER) && (_y < IMG_H - BORDER);      \
        f32x4 _r;                                                         \
        _r[0] = ((VS)[0] == _m[0] && (VS)[0] >= REP_THR && bx0 && _rowok) ? 1.f : 0.f; \
        _r[1] = ((VS)[1] == _m[1] && (VS)[1] >= REP_THR && bx1 && _rowok) ? 1.f : 0.f; \
        _r[2] = ((VS)[2] == _m[2] && (VS)[2] >= REP_THR && bx2 && _rowok) ? 1.f : 0.f; \
        _r[3] = ((VS)[3] == _m[3] && (VS)[3] >= REP_THR && bx3 && _rowok) ? 1.f : 0.f; \
        *(f32x4*)(obase + (size_t)(j) * IMG_W) = _r;                      \
        HMAX((Hp2), (PV), (PL), (PQ));   /* h(row j+2), needed at j+1 */  \
        (VS) = (PV);                     /* center vals of row j+2    */  \
        ISSUE((j) + y0 + 4, (PV), (PL), (PQ));  /* prefetch row j+4   */  \
        __builtin_amdgcn_sched_barrier(0);                                \
    } while (0)

    for (int j = 0; j < SH; j += 4) {
        ITER(j + 0, hS0, hS1, hS2, hS3, pV0, pL0, pQ0, vs0);
        ITER(j + 1, hS1, hS2, hS3, hS0, pV1, pL1, pQ1, vs1);
        ITER(j + 2, hS2, hS3, hS0, hS1, pV0, pL0, pQ0, vs0);
        ITER(j + 3, hS3, hS0, hS1, hS2, pV1, pL1, pQ1, vs1);
    }
#undef ITER
#undef ISSUE
#undef HMAX
#undef CLAMPR
}

extern "C" void kernel_launch(void* const* d_in, const int* in_sizes, int n_in,
                              void* d_out, int out_size, void* d_ws, size_t ws_size,
                              hipStream_t stream) {
    const float* in = (const float*)d_in[0];
    float* out = (float*)d_out;
    const int total_threads = NB * (IMG_H / SH) * (IMG_W / 4);  // 131072
    const int block = 256;
    const int grid = total_threads / block;                     // 512
    nms_kernel<<<grid, block, 0, stream>>>(in, out);
}